// Round 1
// baseline (147.052 us; speedup 1.0000x reference)
//
#include <hip/hip_runtime.h>

// Problem constants from setup_inputs(): shape (64, 16, 64, 64), fp32, kern=2.
#define N_ 64
#define C_ 16
#define H_ 64
#define W_ 64

// pair_kernel tiling (R5 structure): 4 i-rows x 8 j-rows per tile, D split
// into 16 chunks of 1024.
// tri sets (vaa, vbb): i-tile g (rows 4g..4g+3) needs j-tiles 0..(g>>1)
//   -> sum over g=0..15 of (g>>1)+1 = 72 tiles per set
// vab (full): 16 i-tiles x 8 j-tiles = 128 tiles. TILES = 72*2 + 128 = 272.
#define TRI_TILES 72
#define TILES 272
#define DCHUNKS 16
#define PAIR_BLOCKS (TILES * DCHUNKS)   // 4352

// NUMERICS: ws stores var' = var * 2ln2. Then exp(-0.5 d^2/v)/sqrt(v)
//   = exp2(-(d*rsq(v'))^2) * rsq(v') * sqrt(2ln2);
// sqrt(2ln2)=1.1774100 folds into the per-block partial. 5 VALU + 2 transc/term.
#define TWO_LN2   1.3862943611198906f
#define SQRT_2LN2 1.1774100225154747f

// ws layout (floats): [0..Np) mu_a | [Np..2Np) var'_a | [2Np..3Np) mu_b |
// [3Np..4Np) var'_b | [4Np..4Np+PAIR_BLOCKS) per-block partials.
// R7 post-mortem: single-address atomicAdd tail ~6ns x nblocks serialized
// (~26us at 4352 blocks) — replaced by partial stores + 1-block reduce.

__global__ __launch_bounds__(256) void pool_kernel(
    const float* __restrict__ mu_a, const float* __restrict__ lv_a,
    const float* __restrict__ mu_b, const float* __restrict__ lv_b,
    const int* __restrict__ kern_p, float* __restrict__ ws) {
    const int k = kern_p[0];
    const float LOG2E = 1.44269504088896f;

    if (k == 2) {
        // Fast path: 4 contiguous pooled outputs per thread, all-shift indexing.
        const int Np = (N_ * C_ * H_ * W_) >> 2;  // 1048576
        const int Q  = Np >> 2;                   // 262144 quads per array
        const int total = 4 * Q;
        for (int g = blockIdx.x * blockDim.x + threadIdx.x; g < total;
             g += gridDim.x * blockDim.x) {
            const int a  = g >> 18;               // log2(Q) = 18
            const int r4 = g & (Q - 1);
            const int pw4 = (r4 & 7) << 2;        // Wp=32 -> 8 quads/row
            const int t   = r4 >> 3;
            const int ph  = t & 31;               // Hp=32
            const int nc  = t >> 5;
            const float* src = (a == 0) ? mu_a : (a == 1) ? lv_a : (a == 2) ? mu_b : lv_b;
            const bool is_var = (a & 1);
            const float* p0 = src + nc * (H_ * W_) + (ph * 2) * W_ + pw4 * 2;
            float4 r0a = *(const float4*)(p0);
            float4 r0b = *(const float4*)(p0 + 4);
            float4 r1a = *(const float4*)(p0 + W_);
            float4 r1b = *(const float4*)(p0 + W_ + 4);
            float o0, o1, o2, o3;
            if (is_var) {
#define E_(x) __builtin_amdgcn_exp2f((x) * LOG2E)
                o0 = E_(r0a.x) + E_(r0a.y) + E_(r1a.x) + E_(r1a.y);
                o1 = E_(r0a.z) + E_(r0a.w) + E_(r1a.z) + E_(r1a.w);
                o2 = E_(r0b.x) + E_(r0b.y) + E_(r1b.x) + E_(r1b.y);
                o3 = E_(r0b.z) + E_(r0b.w) + E_(r1b.z) + E_(r1b.w);
#undef E_
                const float s = (1.0f / 16.0f) * TWO_LN2;  // 1/k^4 * 2ln2
                o0 *= s; o1 *= s; o2 *= s; o3 *= s;
            } else {
                o0 = r0a.x + r0a.y + r1a.x + r1a.y;
                o1 = r0a.z + r0a.w + r1a.z + r1a.w;
                o2 = r0b.x + r0b.y + r1b.x + r1b.y;
                o3 = r0b.z + r0b.w + r1b.z + r1b.w;
                const float s = 0.25f;            // 1/k^2
                o0 *= s; o1 *= s; o2 *= s; o3 *= s;
            }
            *(float4*)(ws + (size_t)a * Np + (size_t)r4 * 4) = make_float4(o0, o1, o2, o3);
        }
    } else {
        // Generic fallback (any k dividing 64).
        const int Hp = H_ / k, Wp = W_ / k;
        const int Np = N_ * C_ * Hp * Wp;
        const float inv_k2 = 1.0f / (float)(k * k);
        const float inv_k4 = inv_k2 * inv_k2 * TWO_LN2;   // fold var pre-scale
        const int total = 4 * Np;
        for (int p = blockIdx.x * blockDim.x + threadIdx.x; p < total;
             p += gridDim.x * blockDim.x) {
            const int a  = p / Np;
            const int r  = p - a * Np;
            const int pw = r % Wp;
            const int t1 = r / Wp;
            const int ph = t1 % Hp;
            const int nc = t1 / Hp;
            const float* src = (a == 0) ? mu_a : (a == 1) ? lv_a : (a == 2) ? mu_b : lv_b;
            const bool is_var = (a & 1);
            const int base = nc * (H_ * W_) + (ph * k) * W_ + (pw * k);
            float s = 0.0f;
            for (int dy = 0; dy < k; ++dy) {
                const float* row = src + base + dy * W_;
                for (int dx = 0; dx < k; ++dx) {
                    float x = row[dx];
                    s += is_var ? __builtin_amdgcn_exp2f(x * LOG2E) : x;
                }
            }
            ws[(size_t)a * Np + r] = s * (is_var ? inv_k4 : inv_k2);
        }
    }
}

// R8 theory: VGPR_Count=68 < live demand (~78) of the 32-acc body -> compiler
// can't pipeline the j-row loads; each j8 iter exposes an L2/L3-hit latency
// that ~2 resident blocks/CU can't hide (VALUBusy 75%, Occ 26%, ~50cy per
// wave-term vs ~26cy exec cost).
// Fix: (a) uniform-weight specialization — 240/272 tiles have a single weight
// (w=2 off-diag tri, w=-2 vab), so accumulate into acc[ir][component] (16
// regs) and apply the weight once per block. Only the 32 "diagonal" tiles
// fold the 0/1/2 weight per-term (one extra mul). (b) explicit 1-ahead j-row
// prefetch in the unrolled loop so the next jm/jv load issues ~112 instrs
// before first use.
// NOTE: no min-waves clause — R3 showed __launch_bounds__(256,8) forces spills.
__global__ __launch_bounds__(256) void pair_kernel(float* __restrict__ ws,
                                                   const int* __restrict__ kern_p) {
    const int k = kern_p[0];
    const int D  = C_ * (H_ / k) * (W_ / k);
    const int Np = N_ * D;

    const float* mu_a = ws;
    const float* va   = ws + (size_t)Np;
    const float* mu_b = ws + (size_t)2 * Np;
    const float* vb   = ws + (size_t)3 * Np;
    float* partials   = ws + (size_t)4 * Np;

    // ---- decode block -> (set, i-tile, j-tile, chunk) ----
    const int c = blockIdx.x & (DCHUNKS - 1);
    const int t = blockIdx.x >> 4;           // DCHUNKS == 16
    int set, it, jt;
    if (t >= 2 * TRI_TILES) {
        set = 2;
        const int tt = t - 2 * TRI_TILES;
        it = tt >> 3;
        jt = tt & 7;
    } else {
        set = (t >= TRI_TILES) ? 1 : 0;
        const int tt = set ? (t - TRI_TILES) : t;
        int g = 0, cum = 0;
        while (cum + (g >> 1) + 1 <= tt) { cum += (g >> 1) + 1; ++g; }
        it = g;
        jt = tt - cum;
    }
    const int i0 = it * 4, j0 = jt * 8;

    const float *mu1, *v1, *mu2, *v2;
    if (set == 0)      { mu1 = mu2 = mu_a; v1 = v2 = va; }
    else if (set == 1) { mu1 = mu2 = mu_b; v1 = v2 = vb; }
    else               { mu1 = mu_a; v1 = va; mu2 = mu_b; v2 = vb; }

    // Uniform-weight tile? tri i-tile g's j-tiles 0..(g>>1)-1 are strictly
    // below the diagonal (8*jt+7 <= 4g-1 < i0) -> w=2 for all 32 pairs.
    // Only jt == g>>1 mixes weights. Set 2 is uniformly w=-2.
    const bool uniform = (set == 2) || (jt < (it >> 1));
    const float wU = (set == 2) ? -2.0f : 2.0f;

#define TERM(acc, mx1, sx1, mx2, sx2)                                  \
    {                                                                  \
        float v  = (sx1) + (sx2);                                      \
        float rs = __builtin_amdgcn_rsqf(v);                           \
        float d  = (mx1) - (mx2);                                      \
        float t_ = d * rs;                                             \
        float e  = __builtin_amdgcn_exp2f(-(t_ * t_));                 \
        acc = fmaf(e, rs, acc);                                        \
    }
#define TERMW(acc, mx1, sx1, mx2, sx2, w)                              \
    {                                                                  \
        float v  = (sx1) + (sx2);                                      \
        float rs = __builtin_amdgcn_rsqf(v);                           \
        float d  = (mx1) - (mx2);                                      \
        float t_ = d * rs;                                             \
        float e  = __builtin_amdgcn_exp2f(-(t_ * t_));                 \
        acc = fmaf((w), e * rs, acc);                                  \
    }

    // 16 accumulators: [i-row][float4 component]. Dep distance between fmacs
    // to the same acc = 16 terms — no fmac latency chain.
    float acc[4][4];
    #pragma unroll
    for (int ir = 0; ir < 4; ++ir)
        #pragma unroll
        for (int q = 0; q < 4; ++q) acc[ir][q] = 0.0f;

    float wmul = 1.0f;   // applied at the end (uniform fast-path weight)

    if (D == 16384) {
        // Fast path: chunk = 1024 elems = 256 threads x 1 float4.
        const int base = (c << 10) + ((int)threadIdx.x << 2);
        const float* pim = mu1 + (size_t)i0 * 16384 + base;
        const float* piv = v1  + (size_t)i0 * 16384 + base;
        const float* pjm = mu2 + (size_t)j0 * 16384 + base;
        const float* pjv = v2  + (size_t)j0 * 16384 + base;
        float4 im[4], iv[4];
        #pragma unroll
        for (int ir = 0; ir < 4; ++ir) {
            im[ir] = *(const float4*)(pim + (size_t)ir * 16384);
            iv[ir] = *(const float4*)(piv + (size_t)ir * 16384);
        }
        float4 jm = *(const float4*)(pjm);
        float4 jv = *(const float4*)(pjv);
        if (uniform) {
            wmul = wU;
            #pragma unroll
            for (int j8 = 0; j8 < 8; ++j8) {
                float4 nm, nv;
                if (j8 < 7) {   // prefetch next j-row while computing this one
                    nm = *(const float4*)(pjm + (size_t)(j8 + 1) * 16384);
                    nv = *(const float4*)(pjv + (size_t)(j8 + 1) * 16384);
                }
                #pragma unroll
                for (int ir = 0; ir < 4; ++ir) {
                    TERM(acc[ir][0], im[ir].x, iv[ir].x, jm.x, jv.x)
                    TERM(acc[ir][1], im[ir].y, iv[ir].y, jm.y, jv.y)
                    TERM(acc[ir][2], im[ir].z, iv[ir].z, jm.z, jv.z)
                    TERM(acc[ir][3], im[ir].w, iv[ir].w, jm.w, jv.w)
                }
                if (j8 < 7) { jm = nm; jv = nv; }
            }
        } else {
            // Diagonal tile (32 of 272 blocks): fold 0/1/2 weight per term.
            #pragma unroll
            for (int j8 = 0; j8 < 8; ++j8) {
                float4 nm, nv;
                if (j8 < 7) {
                    nm = *(const float4*)(pjm + (size_t)(j8 + 1) * 16384);
                    nv = *(const float4*)(pjv + (size_t)(j8 + 1) * 16384);
                }
                const int jj = j0 + j8;
                #pragma unroll
                for (int ir = 0; ir < 4; ++ir) {
                    const int ii = i0 + ir;
                    const float w = (jj > ii) ? 0.0f : (jj == ii) ? 1.0f : 2.0f;
                    TERMW(acc[ir][0], im[ir].x, iv[ir].x, jm.x, jv.x, w)
                    TERMW(acc[ir][1], im[ir].y, iv[ir].y, jm.y, jv.y, w)
                    TERMW(acc[ir][2], im[ir].z, iv[ir].z, jm.z, jv.z, w)
                    TERMW(acc[ir][3], im[ir].w, iv[ir].w, jm.w, jv.w, w)
                }
                if (j8 < 7) { jm = nm; jv = nv; }
            }
        }
    } else {
        // Generic fallback: chunk c covers [c*D/16, (c+1)*D/16), scalar loads,
        // weight folded per term (acc index j8&3 keeps fmac dep distance >= 4).
        const int cs = D / DCHUNKS;
        const int lo = c * cs, hi = lo + cs;
        for (int e = lo + (int)threadIdx.x; e < hi; e += 256) {
            #pragma unroll
            for (int j8 = 0; j8 < 8; ++j8) {
                const int jj = j0 + j8;
                const float mj = mu2[(size_t)jj * D + e];
                const float vj = v2 [(size_t)jj * D + e];
                #pragma unroll
                for (int ir = 0; ir < 4; ++ir) {
                    const int ii = i0 + ir;
                    const float w = (set == 2) ? -2.0f
                                  : (jj > ii) ? 0.0f : (jj == ii) ? 1.0f : 2.0f;
                    const float mi = mu1[(size_t)ii * D + e];
                    const float vi = v1 [(size_t)ii * D + e];
                    TERMW(acc[ir][j8 & 3], mi, vi, mj, vj, w)
                }
            }
        }
    }
#undef TERM
#undef TERMW

    float tot = 0.0f;
    #pragma unroll
    for (int ir = 0; ir < 4; ++ir)
        #pragma unroll
        for (int q = 0; q < 4; ++q) tot += acc[ir][q];
    tot *= wmul * SQRT_2LN2;   // uniform tile weight + var'-prescale correction

    for (int off = 32; off > 0; off >>= 1)
        tot += __shfl_down(tot, off, 64);
    __shared__ float wsum[4];
    const int lane = threadIdx.x & 63;
    const int wid  = threadIdx.x >> 6;
    if (lane == 0) wsum[wid] = tot;
    __syncthreads();
    if (threadIdx.x == 0) {
        partials[blockIdx.x] = wsum[0] + wsum[1] + wsum[2] + wsum[3];
    }
}

// Single block: sum the PAIR_BLOCKS partials into out[0].
__global__ __launch_bounds__(256) void reduce_kernel(const float* __restrict__ ws,
                                                     const int* __restrict__ kern_p,
                                                     float* __restrict__ out) {
    const int k = kern_p[0];
    const int D  = C_ * (H_ / k) * (W_ / k);
    const int Np = N_ * D;
    const float* partials = ws + (size_t)4 * Np;

    float s = 0.0f;
    for (int p = threadIdx.x; p < PAIR_BLOCKS; p += 256) s += partials[p];
    for (int off = 32; off > 0; off >>= 1)
        s += __shfl_down(s, off, 64);
    __shared__ float wsum[4];
    const int lane = threadIdx.x & 63;
    const int wid  = threadIdx.x >> 6;
    if (lane == 0) wsum[wid] = s;
    __syncthreads();
    if (threadIdx.x == 0) out[0] = wsum[0] + wsum[1] + wsum[2] + wsum[3];
}

extern "C" void kernel_launch(void* const* d_in, const int* in_sizes, int n_in,
                              void* d_out, int out_size, void* d_ws, size_t ws_size,
                              hipStream_t stream) {
    const float* mu_a = (const float*)d_in[0];
    const float* lv_a = (const float*)d_in[1];
    const float* mu_b = (const float*)d_in[2];
    const float* lv_b = (const float*)d_in[3];
    const int*   kern = (const int*)d_in[4];
    float* out = (float*)d_out;
    float* ws  = (float*)d_ws;

    pool_kernel<<<4096, 256, 0, stream>>>(mu_a, lv_a, mu_b, lv_b, kern, ws);
    pair_kernel<<<PAIR_BLOCKS, 256, 0, stream>>>(ws, kern);
    reduce_kernel<<<1, 256, 0, stream>>>(ws, kern, out);
}

// Round 2
// 144.718 us; speedup vs baseline: 1.0161x; 1.0161x over previous
//
#include <hip/hip_runtime.h>

// Problem constants from setup_inputs(): shape (64, 16, 64, 64), fp32, kern=2.
#define N_ 64
#define C_ 16
#define H_ 64
#define W_ 64

// pair_kernel tiling (R5 structure — best measured): 4 i-rows x 8 j-rows per
// tile, D split into 16 chunks of 1024.
// tri sets (vaa, vbb): i-tile g (rows 4g..4g+3) needs j-tiles 0..(g>>1)
//   -> sum over g=0..15 of (g>>1)+1 = 72 tiles per set
// vab (full): 16 i-tiles x 8 j-tiles = 128 tiles. TILES = 72*2 + 128 = 272.
#define TRI_TILES 72
#define TILES 272
#define DCHUNKS 16
#define PAIR_BLOCKS (TILES * DCHUNKS)   // 4352 = 8 XCDs * 544

// NUMERICS: ws stores var' = var * 2ln2. Then exp(-0.5 d^2/v)/sqrt(v)
//   = exp2(-(d*rsq(v'))^2) * rsq(v') * sqrt(2ln2);
// sqrt(2ln2)=1.1774100 folds into the per-block partial. 5 VALU + 2 transc/term.
#define TWO_LN2   1.3862943611198906f
#define SQRT_2LN2 1.1774100225154747f

// ws layout (floats): [0..Np) mu_a | [Np..2Np) var'_a | [2Np..3Np) mu_b |
// [3Np..4Np) var'_b | [4Np..4Np+PAIR_BLOCKS) per-block partials.
// R7 post-mortem: single-address atomicAdd tail serialized -> partials+reduce.
// R8 post-mortem: acc-shrink+manual prefetch -> VGPR 96, occ 18%, dur +4%.
//   Occupancy 1.4x down but time ~flat => NOT latency-bound; VALUBusy fell at
//   flat perf => NOT issue-bound. 428MB/dispatch of L2/LLC reads at 9.4 TB/s
//   => LLC-BW-bound. R9 attacks that via XCD-chunk affinity.

__global__ __launch_bounds__(256) void pool_kernel(
    const float* __restrict__ mu_a, const float* __restrict__ lv_a,
    const float* __restrict__ mu_b, const float* __restrict__ lv_b,
    const int* __restrict__ kern_p, float* __restrict__ ws) {
    const int k = kern_p[0];
    const float LOG2E = 1.44269504088896f;

    if (k == 2) {
        // Fast path: 4 contiguous pooled outputs per thread, all-shift indexing.
        const int Np = (N_ * C_ * H_ * W_) >> 2;  // 1048576
        const int Q  = Np >> 2;                   // 262144 quads per array
        const int total = 4 * Q;
        for (int g = blockIdx.x * blockDim.x + threadIdx.x; g < total;
             g += gridDim.x * blockDim.x) {
            const int a  = g >> 18;               // log2(Q) = 18
            const int r4 = g & (Q - 1);
            const int pw4 = (r4 & 7) << 2;        // Wp=32 -> 8 quads/row
            const int t   = r4 >> 3;
            const int ph  = t & 31;               // Hp=32
            const int nc  = t >> 5;
            const float* src = (a == 0) ? mu_a : (a == 1) ? lv_a : (a == 2) ? mu_b : lv_b;
            const bool is_var = (a & 1);
            const float* p0 = src + nc * (H_ * W_) + (ph * 2) * W_ + pw4 * 2;
            float4 r0a = *(const float4*)(p0);
            float4 r0b = *(const float4*)(p0 + 4);
            float4 r1a = *(const float4*)(p0 + W_);
            float4 r1b = *(const float4*)(p0 + W_ + 4);
            float o0, o1, o2, o3;
            if (is_var) {
#define E_(x) __builtin_amdgcn_exp2f((x) * LOG2E)
                o0 = E_(r0a.x) + E_(r0a.y) + E_(r1a.x) + E_(r1a.y);
                o1 = E_(r0a.z) + E_(r0a.w) + E_(r1a.z) + E_(r1a.w);
                o2 = E_(r0b.x) + E_(r0b.y) + E_(r1b.x) + E_(r1b.y);
                o3 = E_(r0b.z) + E_(r0b.w) + E_(r1b.z) + E_(r1b.w);
#undef E_
                const float s = (1.0f / 16.0f) * TWO_LN2;  // 1/k^4 * 2ln2
                o0 *= s; o1 *= s; o2 *= s; o3 *= s;
            } else {
                o0 = r0a.x + r0a.y + r1a.x + r1a.y;
                o1 = r0a.z + r0a.w + r1a.z + r1a.w;
                o2 = r0b.x + r0b.y + r1b.x + r1b.y;
                o3 = r0b.z + r0b.w + r1b.z + r1b.w;
                const float s = 0.25f;            // 1/k^2
                o0 *= s; o1 *= s; o2 *= s; o3 *= s;
            }
            *(float4*)(ws + (size_t)a * Np + (size_t)r4 * 4) = make_float4(o0, o1, o2, o3);
        }
    } else {
        // Generic fallback (any k dividing 64).
        const int Hp = H_ / k, Wp = W_ / k;
        const int Np = N_ * C_ * Hp * Wp;
        const float inv_k2 = 1.0f / (float)(k * k);
        const float inv_k4 = inv_k2 * inv_k2 * TWO_LN2;   // fold var pre-scale
        const int total = 4 * Np;
        for (int p = blockIdx.x * blockDim.x + threadIdx.x; p < total;
             p += gridDim.x * blockDim.x) {
            const int a  = p / Np;
            const int r  = p - a * Np;
            const int pw = r % Wp;
            const int t1 = r / Wp;
            const int ph = t1 % Hp;
            const int nc = t1 / Hp;
            const float* src = (a == 0) ? mu_a : (a == 1) ? lv_a : (a == 2) ? mu_b : lv_b;
            const bool is_var = (a & 1);
            const int base = nc * (H_ * W_) + (ph * k) * W_ + (pw * k);
            float s = 0.0f;
            for (int dy = 0; dy < k; ++dy) {
                const float* row = src + base + dy * W_;
                for (int dx = 0; dx < k; ++dx) {
                    float x = row[dx];
                    s += is_var ? __builtin_amdgcn_exp2f(x * LOG2E) : x;
                }
            }
            ws[(size_t)a * Np + r] = s * (is_var ? inv_k4 : inv_k2);
        }
    }
}

// R9: exact R5 inner structure (best measured: 45.6us, VGPR 68) + ONE change:
// XCD-chunk affinity. HW round-robins blockIdx across the 8 XCDs, so blocks
// with blockIdx%8 == r land on XCD r. Pin D-chunks {r, r+8} to XCD r: the
// chunk-slice working set (256 row-arrays x 4KB = 1MB/chunk, 2MB for both)
// fits that XCD's 4MB L2. All 428MB of row reads then hit L2 (~34.5 TB/s agg)
// instead of falling through to the Infinity Cache (~9.4 TB/s observed).
// NOTE: no min-waves clause — R3 showed __launch_bounds__(256,8) forces spills.
__global__ __launch_bounds__(256) void pair_kernel(float* __restrict__ ws,
                                                   const int* __restrict__ kern_p) {
    const int k = kern_p[0];
    const int D  = C_ * (H_ / k) * (W_ / k);
    const int Np = N_ * D;

    const float* mu_a = ws;
    const float* va   = ws + (size_t)Np;
    const float* mu_b = ws + (size_t)2 * Np;
    const float* vb   = ws + (size_t)3 * Np;
    float* partials   = ws + (size_t)4 * Np;

    // ---- decode block -> (xcd, chunk, tile) ----
    // blockIdx%8 selects the XCD (hardware round-robin); o = blockIdx/8 is the
    // per-XCD ordinal in [0, 544). Chunk c = (blockIdx%8) + 8*(o >= 272);
    // tile t = o mod 272.
    const int xcd = blockIdx.x & 7;
    const int o   = blockIdx.x >> 3;
    const int c   = xcd + ((o >= TILES) ? 8 : 0);
    const int t   = (o >= TILES) ? (o - TILES) : o;

    int set, it, jt;
    if (t >= 2 * TRI_TILES) {
        set = 2;
        const int tt = t - 2 * TRI_TILES;
        it = tt >> 3;
        jt = tt & 7;
    } else {
        set = (t >= TRI_TILES) ? 1 : 0;
        const int tt = set ? (t - TRI_TILES) : t;
        int g = 0, cum = 0;
        while (cum + (g >> 1) + 1 <= tt) { cum += (g >> 1) + 1; ++g; }
        it = g;
        jt = tt - cum;
    }
    const int i0 = it * 4, j0 = jt * 8;

    const float *mu1, *v1, *mu2, *v2;
    if (set == 0)      { mu1 = mu2 = mu_a; v1 = v2 = va; }
    else if (set == 1) { mu1 = mu2 = mu_b; v1 = v2 = vb; }
    else               { mu1 = mu_a; v1 = va; mu2 = mu_b; v2 = vb; }

#define TERM(acc, mx1, sx1, mx2, sx2)                                  \
    {                                                                  \
        float v  = (sx1) + (sx2);                                      \
        float rs = __builtin_amdgcn_rsqf(v);                           \
        float d  = (mx1) - (mx2);                                      \
        float t_ = d * rs;                                             \
        float e  = __builtin_amdgcn_exp2f(-(t_ * t_));                 \
        acc = fmaf(e, rs, acc);                                        \
    }

    float accs[4][8];
    #pragma unroll
    for (int ir = 0; ir < 4; ++ir)
        #pragma unroll
        for (int j8 = 0; j8 < 8; ++j8) accs[ir][j8] = 0.0f;

    if (D == 16384) {
        // Fast path: chunk = 1024 elems = 256 threads x 1 float4.
        const int base = (c << 10) + ((int)threadIdx.x << 2);
        float4 im[4], iv[4];
        #pragma unroll
        for (int ir = 0; ir < 4; ++ir) {
            im[ir] = *(const float4*)(mu1 + (size_t)(i0 + ir) * 16384 + base);
            iv[ir] = *(const float4*)(v1  + (size_t)(i0 + ir) * 16384 + base);
        }
        #pragma unroll
        for (int j8 = 0; j8 < 8; ++j8) {
            const float4 jm = *(const float4*)(mu2 + (size_t)(j0 + j8) * 16384 + base);
            const float4 jv = *(const float4*)(v2  + (size_t)(j0 + j8) * 16384 + base);
            #pragma unroll
            for (int ir = 0; ir < 4; ++ir) {
                TERM(accs[ir][j8], im[ir].x, iv[ir].x, jm.x, jv.x)
                TERM(accs[ir][j8], im[ir].y, iv[ir].y, jm.y, jv.y)
                TERM(accs[ir][j8], im[ir].z, iv[ir].z, jm.z, jv.z)
                TERM(accs[ir][j8], im[ir].w, iv[ir].w, jm.w, jv.w)
            }
        }
    } else {
        // Generic fallback: chunk c covers [c*D/16, (c+1)*D/16), scalar loads.
        const int cs = D / DCHUNKS;
        const int lo = c * cs, hi = lo + cs;
        for (int e = lo + (int)threadIdx.x; e < hi; e += 256) {
            #pragma unroll
            for (int j8 = 0; j8 < 8; ++j8) {
                const float mj = mu2[(size_t)(j0 + j8) * D + e];
                const float vj = v2 [(size_t)(j0 + j8) * D + e];
                #pragma unroll
                for (int ir = 0; ir < 4; ++ir) {
                    const float mi = mu1[(size_t)(i0 + ir) * D + e];
                    const float vi = v1 [(size_t)(i0 + ir) * D + e];
                    TERM(accs[ir][j8], mi, vi, mj, vj)
                }
            }
        }
    }
#undef TERM

    float tot = 0.0f;
    #pragma unroll
    for (int ir = 0; ir < 4; ++ir) {
        #pragma unroll
        for (int j8 = 0; j8 < 8; ++j8) {
            float w;
            if (set == 2) w = -2.0f;
            else {
                const int ii = i0 + ir, jj = j0 + j8;
                w = (jj > ii) ? 0.0f : (jj == ii) ? 1.0f : 2.0f;
            }
            tot = fmaf(w, accs[ir][j8], tot);
        }
    }
    tot *= SQRT_2LN2;   // fold the var'-prescale correction once

    for (int off = 32; off > 0; off >>= 1)
        tot += __shfl_down(tot, off, 64);
    __shared__ float wsum[4];
    const int lane = threadIdx.x & 63;
    const int wid  = threadIdx.x >> 6;
    if (lane == 0) wsum[wid] = tot;
    __syncthreads();
    if (threadIdx.x == 0) {
        partials[blockIdx.x] = wsum[0] + wsum[1] + wsum[2] + wsum[3];
    }
}

// Single block: sum the PAIR_BLOCKS partials into out[0].
__global__ __launch_bounds__(256) void reduce_kernel(const float* __restrict__ ws,
                                                     const int* __restrict__ kern_p,
                                                     float* __restrict__ out) {
    const int k = kern_p[0];
    const int D  = C_ * (H_ / k) * (W_ / k);
    const int Np = N_ * D;
    const float* partials = ws + (size_t)4 * Np;

    float s = 0.0f;
    for (int p = threadIdx.x; p < PAIR_BLOCKS; p += 256) s += partials[p];
    for (int off = 32; off > 0; off >>= 1)
        s += __shfl_down(s, off, 64);
    __shared__ float wsum[4];
    const int lane = threadIdx.x & 63;
    const int wid  = threadIdx.x >> 6;
    if (lane == 0) wsum[wid] = s;
    __syncthreads();
    if (threadIdx.x == 0) out[0] = wsum[0] + wsum[1] + wsum[2] + wsum[3];
}

extern "C" void kernel_launch(void* const* d_in, const int* in_sizes, int n_in,
                              void* d_out, int out_size, void* d_ws, size_t ws_size,
                              hipStream_t stream) {
    const float* mu_a = (const float*)d_in[0];
    const float* lv_a = (const float*)d_in[1];
    const float* mu_b = (const float*)d_in[2];
    const float* lv_b = (const float*)d_in[3];
    const int*   kern = (const int*)d_in[4];
    float* out = (float*)d_out;
    float* ws  = (float*)d_ws;

    pool_kernel<<<4096, 256, 0, stream>>>(mu_a, lv_a, mu_b, lv_b, kern, ws);
    pair_kernel<<<PAIR_BLOCKS, 256, 0, stream>>>(ws, kern);
    reduce_kernel<<<1, 256, 0, stream>>>(ws, kern, out);
}